// Round 1
// baseline (2497.672 us; speedup 1.0000x reference)
//
#include <hip/hip_runtime.h>

// UniversalSAE: z = TopK32((x - pre_bias) @ enc_w.T), rec_i = z @ dec_w_i.T + post_bias_i
// R1 baseline: fp32 tiled GEMM (precision-critical for top-k index selection) +
// exact radix-select top-32 per row + sparse decode via transposed dec weights in ws.

#define BATCH  16384
#define HIDDEN 8192
#define DIM0   512
#define DIM1   768
#define TOPK   32

__device__ __forceinline__ unsigned fkey(float f) {
    unsigned u = __float_as_uint(f);
    return (u & 0x80000000u) ? ~u : (u | 0x80000000u);  // order-preserving map
}

// ---------------------------------------------------------------------------
// Encode GEMM: z[B,H] = (x - pb) @ W^T   (x:[B,D] row-major, W:[H,D] row-major)
// 128x128 tile, BK=16, 256 threads, 8x8 micro-tile (2x2 of 4x4 quadrants).
// fp32 FMA, ascending-k accumulation order (single accumulator per output).
// ---------------------------------------------------------------------------
__global__ __launch_bounds__(256, 2)
void encode_gemm(const float* __restrict__ x0, const float* __restrict__ x1,
                 const float* __restrict__ pb0, const float* __restrict__ pb1,
                 const float* __restrict__ w0, const float* __restrict__ w1,
                 const int* __restrict__ srcp, float* __restrict__ z)
{
    const int src = *srcp;
    const float* __restrict__ x  = (src == 0) ? x0 : x1;
    const float* __restrict__ pb = (src == 0) ? pb0 : pb1;
    const float* __restrict__ w  = (src == 0) ? w0 : w1;
    const int D = (src == 0) ? DIM0 : DIM1;

    __shared__ float As[16][132];   // [k][m], pad 132 to spread banks
    __shared__ float Bs[16][132];   // [k][n]

    const int tid = threadIdx.x;
    const int m0 = blockIdx.y * 128;
    const int n0 = blockIdx.x * 128;

    // staging chunk mapping: 512 float4 chunks per tile, 2 per thread
    const int ar0 = tid >> 1;                 // unused placeholder removed below
    (void)ar0;
    const int cA0 = tid,          cA1 = tid + 256;
    const int r0  = cA0 >> 2,     kq0 = (cA0 & 3) * 4;
    const int r1  = cA1 >> 2,     kq1 = (cA1 & 3) * 4;

    const int mf = (tid & 15) * 4;            // row fragment base (0..60)
    const int nf = (tid >> 4) * 4;            // col fragment base (0..60)

    float acc[8][8];
#pragma unroll
    for (int i = 0; i < 8; ++i)
#pragma unroll
        for (int j = 0; j < 8; ++j) acc[i][j] = 0.0f;

    for (int k0 = 0; k0 < D; k0 += 16) {
        // ---- stage A (x - pb) and B (W) tiles ----
        {
            const float4 av0 = *(const float4*)(x + (size_t)(m0 + r0) * D + k0 + kq0);
            const float4 av1 = *(const float4*)(x + (size_t)(m0 + r1) * D + k0 + kq1);
            const float4 pv0 = *(const float4*)(pb + k0 + kq0);
            const float4 pv1 = *(const float4*)(pb + k0 + kq1);
            const float4 bv0 = *(const float4*)(w + (size_t)(n0 + r0) * D + k0 + kq0);
            const float4 bv1 = *(const float4*)(w + (size_t)(n0 + r1) * D + k0 + kq1);
            As[kq0 + 0][r0] = av0.x - pv0.x;
            As[kq0 + 1][r0] = av0.y - pv0.y;
            As[kq0 + 2][r0] = av0.z - pv0.z;
            As[kq0 + 3][r0] = av0.w - pv0.w;
            As[kq1 + 0][r1] = av1.x - pv1.x;
            As[kq1 + 1][r1] = av1.y - pv1.y;
            As[kq1 + 2][r1] = av1.z - pv1.z;
            As[kq1 + 3][r1] = av1.w - pv1.w;
            Bs[kq0 + 0][r0] = bv0.x;
            Bs[kq0 + 1][r0] = bv0.y;
            Bs[kq0 + 2][r0] = bv0.z;
            Bs[kq0 + 3][r0] = bv0.w;
            Bs[kq1 + 0][r1] = bv1.x;
            Bs[kq1 + 1][r1] = bv1.y;
            Bs[kq1 + 2][r1] = bv1.z;
            Bs[kq1 + 3][r1] = bv1.w;
        }
        __syncthreads();
#pragma unroll
        for (int kk = 0; kk < 16; ++kk) {
            const float4 A0 = *(const float4*)&As[kk][mf];
            const float4 A1 = *(const float4*)&As[kk][mf + 64];
            const float4 B0 = *(const float4*)&Bs[kk][nf];
            const float4 B1 = *(const float4*)&Bs[kk][nf + 64];
            const float a[8] = {A0.x, A0.y, A0.z, A0.w, A1.x, A1.y, A1.z, A1.w};
            const float b[8] = {B0.x, B0.y, B0.z, B0.w, B1.x, B1.y, B1.z, B1.w};
#pragma unroll
            for (int i = 0; i < 8; ++i)
#pragma unroll
                for (int j = 0; j < 8; ++j)
                    acc[i][j] = fmaf(a[i], b[j], acc[i][j]);
        }
        __syncthreads();
    }

#pragma unroll
    for (int i = 0; i < 8; ++i) {
        const int row = m0 + mf + (i & 3) + (i >> 2) * 64;
        const float4 v0 = make_float4(acc[i][0], acc[i][1], acc[i][2], acc[i][3]);
        const float4 v1 = make_float4(acc[i][4], acc[i][5], acc[i][6], acc[i][7]);
        *(float4*)(z + (size_t)row * HIDDEN + n0 + nf)      = v0;
        *(float4*)(z + (size_t)row * HIDDEN + n0 + nf + 64) = v1;
    }
}

// ---------------------------------------------------------------------------
// Transpose dec_w [DD, HIDDEN] -> decT [HIDDEN, DD] in workspace (coalesced decode).
// ---------------------------------------------------------------------------
__global__ void transpose_dec(const float* __restrict__ dec, float* __restrict__ decT, int DD)
{
    __shared__ float t[32][33];
    const int hb = blockIdx.x * 32, db = blockIdx.y * 32;
    const int lx = threadIdx.x, ly = threadIdx.y;
#pragma unroll
    for (int s = 0; s < 32; s += 8)
        t[ly + s][lx] = dec[(size_t)(db + ly + s) * HIDDEN + hb + lx];
    __syncthreads();
#pragma unroll
    for (int s = 0; s < 32; s += 8)
        decT[(size_t)(hb + ly + s) * DD + db + lx] = t[lx][ly + s];
}

// ---------------------------------------------------------------------------
// Per-row exact top-32 (radix select on sortable u32 keys, lowest-index ties)
// + sparse rewrite of z row + sparse decode to rec0/rec1.
// One block per row, 256 threads.
// ---------------------------------------------------------------------------
template<bool USET>
__global__ __launch_bounds__(256, 2)
void topk_decode(float* __restrict__ z,
                 const float* __restrict__ dA,   // USET ? decT0[H,512] : dec0[512,H]
                 const float* __restrict__ dB,   // USET ? decT1[H,768] : dec1[768,H]
                 const float* __restrict__ po0, const float* __restrict__ po1,
                 float* __restrict__ rec0, float* __restrict__ rec1)
{
    __shared__ float    row[HIDDEN];       // 32 KB
    __shared__ unsigned hist[4][257];      // 4 sub-hists, pad 257 to spread banks
    __shared__ unsigned scanbuf[256];
    __shared__ float    selv[TOPK];
    __shared__ int      seli[TOPK];
    __shared__ unsigned sh_byte, sh_gt;

    const int tid = threadIdx.x;
    const size_t rowid = blockIdx.x;
    float* __restrict__ zrow = z + rowid * HIDDEN;

    // load row (coalesced float4, lane-contiguous)
#pragma unroll
    for (int s = 0; s < 8; ++s) {
        const int i4 = s * 256 + tid;
        *(float4*)&row[i4 * 4] = *(const float4*)&zrow[i4 * 4];
    }
    __syncthreads();

    // ---- 4-pass radix select: find exact key of the 32nd-largest value ----
    unsigned prefix = 0, prefmask = 0, need = TOPK;
#pragma unroll
    for (int p = 3; p >= 0; --p) {
        for (int i = tid; i < 4 * 257; i += 256) (&hist[0][0])[i] = 0;
        __syncthreads();
        const int sh = p * 8;
        for (int s = 0; s < 32; ++s) {
            const int i = s * 256 + tid;                 // strided: conflict-free
            const unsigned k = fkey(row[i]);
            if ((k & prefmask) == prefix)
                atomicAdd(&hist[tid & 3][(k >> sh) & 255], 1);
        }
        __syncthreads();
        const unsigned tot = hist[0][tid] + hist[1][tid] + hist[2][tid] + hist[3][tid];
        hist[0][tid] = tot;
        __syncthreads();
        if (tid == 0) {
            unsigned cum = 0;
            int b = 255;
            for (;; --b) {
                const unsigned c = hist[0][b];
                if (cum + c >= need || b == 0) { sh_byte = (unsigned)b; sh_gt = cum; break; }
                cum += c;
            }
        }
        __syncthreads();
        prefix  |= sh_byte << sh;
        prefmask |= 0xFFu << sh;
        need -= sh_gt;
        __syncthreads();
    }
    const unsigned cut = prefix;
    const unsigned needEq = need;   // how many of the ==cut ties to keep (lowest idx first)

    // ---- per-thread masks over its 32 contiguous elements (rotated reads) ----
    unsigned gtmask = 0, eqmask = 0;
#pragma unroll
    for (int j = 0; j < 32; ++j) {
        const int jr = (j + tid) & 31;
        const int i = tid * 32 + jr;
        const unsigned k = fkey(row[i]);
        if (k > cut)       gtmask |= 1u << jr;
        else if (k == cut) eqmask |= 1u << jr;
    }

    // block scan of eq-counts -> index-ordered tie ranks
    scanbuf[tid] = __popc(eqmask);
    __syncthreads();
    for (int off = 1; off < 256; off <<= 1) {
        const unsigned v = scanbuf[tid];
        const unsigned add = (tid >= off) ? scanbuf[tid - off] : 0u;
        __syncthreads();
        scanbuf[tid] = v + add;
        __syncthreads();
    }
    const unsigned eqexc = scanbuf[tid] - __popc(eqmask);
    __syncthreads();

    unsigned selmask = gtmask;
    {
        unsigned m = eqmask, r = eqexc;
        while (m) {
            const int j = __ffs(m) - 1;
            if (r < needEq) selmask |= 1u << j;
            ++r;
            m &= m - 1;
        }
    }

    // block scan of sel-counts -> deterministic slots in ascending index order
    scanbuf[tid] = __popc(selmask);
    __syncthreads();
    for (int off = 1; off < 256; off <<= 1) {
        const unsigned v = scanbuf[tid];
        const unsigned add = (tid >= off) ? scanbuf[tid - off] : 0u;
        __syncthreads();
        scanbuf[tid] = v + add;
        __syncthreads();
    }
    const unsigned selexc = scanbuf[tid] - __popc(selmask);

#pragma unroll
    for (int j = 0; j < 32; ++j) {
        const int jr = (j + tid) & 31;
        const int i = tid * 32 + jr;
        if ((selmask >> jr) & 1u) {
            const int slot = (int)(selexc + __popc(selmask & ((1u << jr) - 1u)));
            selv[slot] = row[i];
            seli[slot] = i;
        } else {
            row[i] = 0.0f;
        }
    }
    __syncthreads();

    // write sparse z row back
#pragma unroll
    for (int s = 0; s < 8; ++s) {
        const int i4 = s * 256 + tid;
        *(float4*)&zrow[i4 * 4] = *(float4*)&row[i4 * 4];
    }

    // ---- sparse decode: rec = sum_j selv[j] * dec[:, seli[j]] + post_bias ----
    for (int d = tid; d < DIM0; d += 256) {
        float a = po0[d];
#pragma unroll
        for (int j = 0; j < TOPK; ++j) {
            const float wv = USET ? dA[(size_t)seli[j] * DIM0 + d]
                                  : dA[(size_t)d * HIDDEN + seli[j]];
            a = fmaf(selv[j], wv, a);
        }
        rec0[rowid * DIM0 + d] = a;
    }
    for (int d = tid; d < DIM1; d += 256) {
        float a = po1[d];
#pragma unroll
        for (int j = 0; j < TOPK; ++j) {
            const float wv = USET ? dB[(size_t)seli[j] * DIM1 + d]
                                  : dB[(size_t)d * HIDDEN + seli[j]];
            a = fmaf(selv[j], wv, a);
        }
        rec1[rowid * DIM1 + d] = a;
    }
}

// ---------------------------------------------------------------------------
extern "C" void kernel_launch(void* const* d_in, const int* in_sizes, int n_in,
                              void* d_out, int out_size, void* d_ws, size_t ws_size,
                              hipStream_t stream)
{
    const float* x0  = (const float*)d_in[0];
    const float* x1  = (const float*)d_in[1];
    const float* pb0 = (const float*)d_in[2];
    const float* pb1 = (const float*)d_in[3];
    const float* ew0 = (const float*)d_in[4];
    const float* ew1 = (const float*)d_in[5];
    const float* dw0 = (const float*)d_in[6];
    const float* dw1 = (const float*)d_in[7];
    const float* po0 = (const float*)d_in[8];
    const float* po1 = (const float*)d_in[9];
    const int*  srcp = (const int*)d_in[10];

    float* z    = (float*)d_out;
    float* rec0 = z + (size_t)BATCH * HIDDEN;
    float* rec1 = rec0 + (size_t)BATCH * DIM0;

    const size_t needT = (size_t)HIDDEN * (DIM0 + DIM1) * sizeof(float);
    const bool useT = (ws_size >= needT);
    float* decT0 = (float*)d_ws;
    float* decT1 = decT0 + (size_t)HIDDEN * DIM0;

    if (useT) {
        dim3 tb(32, 8);
        transpose_dec<<<dim3(HIDDEN / 32, DIM0 / 32), tb, 0, stream>>>(dw0, decT0, DIM0);
        transpose_dec<<<dim3(HIDDEN / 32, DIM1 / 32), tb, 0, stream>>>(dw1, decT1, DIM1);
    }

    encode_gemm<<<dim3(HIDDEN / 128, BATCH / 128), 256, 0, stream>>>(
        x0, x1, pb0, pb1, ew0, ew1, srcp, z);

    if (useT)
        topk_decode<true><<<BATCH, 256, 0, stream>>>(z, decT0, decT1, po0, po1, rec0, rec1);
    else
        topk_decode<false><<<BATCH, 256, 0, stream>>>(z, dw0, dw1, po0, po1, rec0, rec1);
}

// Round 2
// 887.022 us; speedup vs baseline: 2.8158x; 2.8158x over previous
//
#include <hip/hip_runtime.h>

// UniversalSAE: z = TopK32((x - pre_bias) @ enc_w.T), rec_i = z @ dec_w_i.T + post_bias_i
// R2: bf16 MFMA screening GEMM + exact fp32 rescore of ~36-128 candidates/row
// (bitwise-identical accumulation order to the round-1 passing kernel) +
// bisection-based candidate threshold (no histogram atomics) + bf16 transposed decode.

#define BATCH  16384
#define HIDDEN 8192
#define DIM0   512
#define DIM1   768
#define TOPK   32
#define CAND_MAX 128

typedef __attribute__((ext_vector_type(8))) short bf16x8;
typedef __attribute__((ext_vector_type(4))) float f32x4;

__device__ __forceinline__ unsigned fkey(float f) {
    unsigned u = __float_as_uint(f);
    return (u & 0x80000000u) ? ~u : (u | 0x80000000u);  // order-preserving map
}

__device__ __forceinline__ unsigned short f2b(float f) {  // fp32 -> bf16 RNE
    unsigned u = __float_as_uint(f);
    unsigned r = (u + 0x7FFFu + ((u >> 16) & 1u)) >> 16;
    return (unsigned short)r;
}
__device__ __forceinline__ float b2f(unsigned short h) {
    return __uint_as_float(((unsigned)h) << 16);
}

__device__ __forceinline__ void load_lds16(const void* g, void* l) {
    __builtin_amdgcn_global_load_lds((const __attribute__((address_space(1))) void*)g,
                                     (__attribute__((address_space(3))) void*)l, 16, 0, 0);
}

// ===========================================================================
// NEW PATH
// ===========================================================================

// ---- convert x-pb and enc_w to bf16 (row stride = runtime D) ----
__global__ void convert_xw(const float* __restrict__ x0, const float* __restrict__ x1,
                           const float* __restrict__ pb0, const float* __restrict__ pb1,
                           const float* __restrict__ w0, const float* __restrict__ w1,
                           const int* __restrict__ srcp,
                           unsigned short* __restrict__ xb, unsigned short* __restrict__ wb)
{
    const int src = *srcp;
    const float* __restrict__ x  = src ? x1  : x0;
    const float* __restrict__ pb = src ? pb1 : pb0;
    const float* __restrict__ w  = src ? w1  : w0;
    const int D = src ? DIM1 : DIM0;
    const int nx4 = BATCH * D / 4;
    const int nw4 = HIDDEN * D / 4;
    for (int i = blockIdx.x * blockDim.x + threadIdx.x; i < nx4 + nw4;
         i += gridDim.x * blockDim.x) {
        if (i < nx4) {
            float4 v = ((const float4*)x)[i];
            const int k = (i * 4) % D;
            v.x -= pb[k]; v.y -= pb[k + 1]; v.z -= pb[k + 2]; v.w -= pb[k + 3];
            ushort4 o; o.x = f2b(v.x); o.y = f2b(v.y); o.z = f2b(v.z); o.w = f2b(v.w);
            ((ushort4*)xb)[i] = o;
        } else {
            const float4 v = ((const float4*)w)[i - nx4];
            ushort4 o; o.x = f2b(v.x); o.y = f2b(v.y); o.z = f2b(v.z); o.w = f2b(v.w);
            ((ushort4*)wb)[i - nx4] = o;
        }
    }
}

// ---- transpose dec_w [DD, HIDDEN] -> bf16 decT [HIDDEN, DD] ----
__global__ void transpose_dec_bf16(const float* __restrict__ dec,
                                   unsigned short* __restrict__ decT, int DD)
{
    __shared__ float t[32][33];
    const int hb = blockIdx.x * 32, db = blockIdx.y * 32;
    const int lx = threadIdx.x, ly = threadIdx.y;
#pragma unroll
    for (int s = 0; s < 32; s += 8)
        t[ly + s][lx] = dec[(size_t)(db + ly + s) * HIDDEN + hb + lx];
    __syncthreads();
#pragma unroll
    for (int s = 0; s < 32; s += 8)
        decT[(size_t)(hb + ly + s) * DD + db + lx] = f2b(t[lx][ly + s]);
}

// ---- bf16 MFMA GEMM: zt[B,H] = xb @ wb^T (both row-major [*,D], K-contiguous) ----
// 128x128 tile, BK=64, 4 waves, per-wave 64x64 (4x4 of 16x16x32 MFMA).
// LDS XOR-swizzle (slot ^= row&7) applied on BOTH stage-source and read (rule #21).
__global__ __launch_bounds__(256, 2)
void gemm_bf16(const unsigned short* __restrict__ xb, const unsigned short* __restrict__ wb,
               const int* __restrict__ srcp, float* __restrict__ z)
{
    const int D = (*srcp == 0) ? DIM0 : DIM1;

    __shared__ unsigned short As[128 * 64];
    __shared__ unsigned short Bs[128 * 64];

    // XCD-aware swizzle of linear block id (nwg = 8192, divisible by 8)
    const int nwg = gridDim.x;
    int id = blockIdx.x;
    id = (id & 7) * (nwg >> 3) + (id >> 3);
    const int bx = id & 63;      // 64 N-blocks
    const int by = id >> 6;      // 128 M-blocks
    const int m0 = by * 128, n0 = bx * 128;

    const int tid  = threadIdx.x;
    const int lane = tid & 63;
    const int wid  = tid >> 6;         // 4 waves
    const int wr   = wid >> 1;         // 2x2 wave grid
    const int wc   = wid & 1;
    const int l15  = lane & 15;
    const int g    = lane >> 4;

    f32x4 acc[4][4];
#pragma unroll
    for (int i = 0; i < 4; ++i)
#pragma unroll
        for (int j = 0; j < 4; ++j) acc[i][j] = (f32x4){0.f, 0.f, 0.f, 0.f};

    for (int k0 = 0; k0 < D; k0 += 64) {
        // stage: 1024 16B chunks per operand; chunk c -> row=c>>3, slot jb=c&7,
        // content = global k-block (jb ^ (row&7))  [pre-swizzled source]
#pragma unroll
        for (int q = 0; q < 4; ++q) {
            const int c   = wid * 256 + q * 64 + lane;
            const int row = c >> 3, jb = c & 7;
            const int j   = jb ^ (row & 7);
            load_lds16(xb + (size_t)(m0 + row) * D + k0 + j * 8,
                       As + (size_t)(wid * 256 + q * 64) * 8);
            load_lds16(wb + (size_t)(n0 + row) * D + k0 + j * 8,
                       Bs + (size_t)(wid * 256 + q * 64) * 8);
        }
        __syncthreads();

#pragma unroll
        for (int kk = 0; kk < 2; ++kk) {
            bf16x8 a[4], b[4];
#pragma unroll
            for (int f = 0; f < 4; ++f) {
                const int rA = wr * 64 + f * 16 + l15;
                const int sA = ((kk * 4 + g) ^ (rA & 7)) * 16;
                a[f] = *(const bf16x8*)((const char*)As + rA * 128 + sA);
                const int rB = wc * 64 + f * 16 + l15;
                const int sB = ((kk * 4 + g) ^ (rB & 7)) * 16;
                b[f] = *(const bf16x8*)((const char*)Bs + rB * 128 + sB);
            }
#pragma unroll
            for (int fi = 0; fi < 4; ++fi)
#pragma unroll
                for (int fj = 0; fj < 4; ++fj)
                    acc[fi][fj] = __builtin_amdgcn_mfma_f32_16x16x32_bf16(
                        a[fi], b[fj], acc[fi][fj], 0, 0, 0);
        }
        __syncthreads();
    }

    // epilogue: C/D layout col=lane&15, row=(lane>>4)*4+r  [m89-verified]
#pragma unroll
    for (int fi = 0; fi < 4; ++fi) {
        const int row = m0 + wr * 64 + fi * 16 + g * 4;
#pragma unroll
        for (int fj = 0; fj < 4; ++fj) {
            const int col = n0 + wc * 64 + fj * 16 + l15;
#pragma unroll
            for (int r = 0; r < 4; ++r)
                z[(size_t)(row + r) * HIDDEN + col] = acc[fi][fj][r];
        }
    }
}

// ---- per-row: bisect approx threshold -> candidates -> exact fp32 rescore
//      -> exact top-32 -> sparse z + decode ----
__global__ __launch_bounds__(256)
void topk_rescore_decode(float* __restrict__ z,
                         const float* __restrict__ x0, const float* __restrict__ x1,
                         const float* __restrict__ pb0, const float* __restrict__ pb1,
                         const float* __restrict__ ew0, const float* __restrict__ ew1,
                         const unsigned short* __restrict__ dTb0,
                         const unsigned short* __restrict__ dTb1,
                         const float* __restrict__ po0, const float* __restrict__ po1,
                         float* __restrict__ rec0, float* __restrict__ rec1,
                         const int* __restrict__ srcp)
{
    const int src = *srcp;
    const float* __restrict__ xsrc = src ? x1 : x0;
    const float* __restrict__ pb   = src ? pb1 : pb0;
    const float* __restrict__ ew   = src ? ew1 : ew0;
    const int D = src ? DIM1 : DIM0;

    __shared__ float         xs[DIM1];          // (x - pb) row, fp32
    __shared__ int           cidx[CAND_MAX];
    __shared__ float         cval[CAND_MAX];
    __shared__ unsigned char cflag[CAND_MAX];
    __shared__ int           counts[4];
    __shared__ int           s_cnt;
    __shared__ float         selv[TOPK];
    __shared__ int           seli[TOPK];

    const int tid = threadIdx.x;
    const size_t row = blockIdx.x;
    float* __restrict__ zrow = z + row * HIDDEN;

    // approx keys into registers (thread owns float4 chunks s*256+tid)
    unsigned key[32];
#pragma unroll
    for (int s = 0; s < 8; ++s) {
        const float4 v = *(const float4*)&zrow[(size_t)(s * 256 + tid) * 4];
        key[s * 4 + 0] = fkey(v.x);
        key[s * 4 + 1] = fkey(v.y);
        key[s * 4 + 2] = fkey(v.z);
        key[s * 4 + 3] = fkey(v.w);
    }

    // stage exact (x - pb) row
    for (int d = tid; d < D; d += 256) xs[d] = xsrc[row * D + d] - pb[d];
    if (tid == 0) s_cnt = 0;
    // (first bisect barrier orders xs/s_cnt for later phases)

    // bisect u32 key space: find kappa with count(key > kappa) in [36, 72]
    unsigned lo = 0u, hi = 0xFFFFFFFFu, kappa = 0u;
    int found = 0;
    for (int it = 0; it < 30; ++it) {
        const unsigned mid = lo + ((hi - lo) >> 1);
        int c = 0;
#pragma unroll
        for (int j = 0; j < 32; ++j) c += (key[j] > mid) ? 1 : 0;
#pragma unroll
        for (int off = 32; off; off >>= 1) c += __shfl_xor(c, off);
        if ((tid & 63) == 0) counts[tid >> 6] = c;
        __syncthreads();
        const int tot = counts[0] + counts[1] + counts[2] + counts[3];
        __syncthreads();
        if (tot >= 36 && tot <= 72) { kappa = mid; found = 1; break; }
        if (tot > 72) lo = mid; else hi = mid;
        if (hi - lo <= 1u) break;
    }
    if (!found) kappa = lo;   // count(lo) > 72 invariant (>=36 guaranteed)

    // collect candidates (order irrelevant; exact values come from rescore)
#pragma unroll
    for (int j = 0; j < 32; ++j) {
        if (key[j] > kappa) {
            const int slot = atomicAdd(&s_cnt, 1);
            if (slot < CAND_MAX)
                cidx[slot] = (j >> 2) * 1024 + tid * 4 + (j & 3);
        }
    }
    __syncthreads();
    const int C = min(s_cnt, CAND_MAX);

    // exact fp32 rescore: sequential ascending-k fmaf chain — bitwise identical
    // to the round-1 passing kernel's accumulation
    if (tid < C) {
        const float* __restrict__ wrow = ew + (size_t)cidx[tid] * D;
        float a = 0.0f;
        for (int k = 0; k < D; k += 4) {
            const float4 wv = *(const float4*)&wrow[k];
            a = fmaf(xs[k + 0], wv.x, a);
            a = fmaf(xs[k + 1], wv.y, a);
            a = fmaf(xs[k + 2], wv.z, a);
            a = fmaf(xs[k + 3], wv.w, a);
        }
        cval[tid] = a;
    }
    __syncthreads();

    // exact top-32 among C candidates (val desc, idx asc)
    if (tid < C) {
        const float v = cval[tid];
        const int  ix = cidx[tid];
        int rank = 0;
        for (int j = 0; j < C; ++j) {
            const float vj = cval[j];
            rank += (vj > v || (vj == v && cidx[j] < ix)) ? 1 : 0;
        }
        cflag[tid] = (rank < TOPK) ? 1 : 0;
    }
    __syncthreads();
    if (tid < C && cflag[tid]) {
        const int ix = cidx[tid];
        int sr = 0;
        for (int j = 0; j < C; ++j) sr += (cflag[j] && cidx[j] < ix) ? 1 : 0;
        selv[sr] = cval[tid];
        seli[sr] = ix;
    }
    __syncthreads();

    // write sparse z row: zeros + 32 exact values
    const float4 z4 = make_float4(0.f, 0.f, 0.f, 0.f);
#pragma unroll
    for (int s = 0; s < 8; ++s)
        *(float4*)&zrow[(size_t)(s * 256 + tid) * 4] = z4;
    __syncthreads();
    if (tid < TOPK) zrow[seli[tid]] = selv[tid];

    // sparse decode (ascending slot order = ascending index, as round-1)
    for (int d = tid; d < DIM0; d += 256) {
        float a = po0[d];
#pragma unroll
        for (int j = 0; j < TOPK; ++j)
            a = fmaf(selv[j], b2f(dTb0[(size_t)seli[j] * DIM0 + d]), a);
        rec0[row * DIM0 + d] = a;
    }
    for (int d = tid; d < DIM1; d += 256) {
        float a = po1[d];
#pragma unroll
        for (int j = 0; j < TOPK; ++j)
            a = fmaf(selv[j], b2f(dTb1[(size_t)seli[j] * DIM1 + d]), a);
        rec1[row * DIM1 + d] = a;
    }
}

// ===========================================================================
// FALLBACK PATH (round-1, known-pass) — used only if ws is too small
// ===========================================================================

__global__ __launch_bounds__(256, 2)
void encode_gemm(const float* __restrict__ x0, const float* __restrict__ x1,
                 const float* __restrict__ pb0, const float* __restrict__ pb1,
                 const float* __restrict__ w0, const float* __restrict__ w1,
                 const int* __restrict__ srcp, float* __restrict__ z)
{
    const int src = *srcp;
    const float* __restrict__ x  = (src == 0) ? x0 : x1;
    const float* __restrict__ pb = (src == 0) ? pb0 : pb1;
    const float* __restrict__ w  = (src == 0) ? w0 : w1;
    const int D = (src == 0) ? DIM0 : DIM1;

    __shared__ float As[16][132];
    __shared__ float Bs[16][132];

    const int tid = threadIdx.x;
    const int m0 = blockIdx.y * 128;
    const int n0 = blockIdx.x * 128;

    const int cA0 = tid,          cA1 = tid + 256;
    const int r0  = cA0 >> 2,     kq0 = (cA0 & 3) * 4;
    const int r1  = cA1 >> 2,     kq1 = (cA1 & 3) * 4;

    const int mf = (tid & 15) * 4;
    const int nf = (tid >> 4) * 4;

    float acc[8][8];
#pragma unroll
    for (int i = 0; i < 8; ++i)
#pragma unroll
        for (int j = 0; j < 8; ++j) acc[i][j] = 0.0f;

    for (int k0 = 0; k0 < D; k0 += 16) {
        const float4 av0 = *(const float4*)(x + (size_t)(m0 + r0) * D + k0 + kq0);
        const float4 av1 = *(const float4*)(x + (size_t)(m0 + r1) * D + k0 + kq1);
        const float4 pv0 = *(const float4*)(pb + k0 + kq0);
        const float4 pv1 = *(const float4*)(pb + k0 + kq1);
        const float4 bv0 = *(const float4*)(w + (size_t)(n0 + r0) * D + k0 + kq0);
        const float4 bv1 = *(const float4*)(w + (size_t)(n0 + r1) * D + k0 + kq1);
        As[kq0 + 0][r0] = av0.x - pv0.x;
        As[kq0 + 1][r0] = av0.y - pv0.y;
        As[kq0 + 2][r0] = av0.z - pv0.z;
        As[kq0 + 3][r0] = av0.w - pv0.w;
        As[kq1 + 0][r1] = av1.x - pv1.x;
        As[kq1 + 1][r1] = av1.y - pv1.y;
        As[kq1 + 2][r1] = av1.z - pv1.z;
        As[kq1 + 3][r1] = av1.w - pv1.w;
        Bs[kq0 + 0][r0] = bv0.x;
        Bs[kq0 + 1][r0] = bv0.y;
        Bs[kq0 + 2][r0] = bv0.z;
        Bs[kq0 + 3][r0] = bv0.w;
        Bs[kq1 + 0][r1] = bv1.x;
        Bs[kq1 + 1][r1] = bv1.y;
        Bs[kq1 + 2][r1] = bv1.z;
        Bs[kq1 + 3][r1] = bv1.w;
        __syncthreads();
#pragma unroll
        for (int kk = 0; kk < 16; ++kk) {
            const float4 A0 = *(const float4*)&As[kk][mf];
            const float4 A1 = *(const float4*)&As[kk][mf + 64];
            const float4 B0 = *(const float4*)&Bs[kk][nf];
            const float4 B1 = *(const float4*)&Bs[kk][nf + 64];
            const float a[8] = {A0.x, A0.y, A0.z, A0.w, A1.x, A1.y, A1.z, A1.w};
            const float b[8] = {B0.x, B0.y, B0.z, B0.w, B1.x, B1.y, B1.z, B1.w};
#pragma unroll
            for (int i = 0; i < 8; ++i)
#pragma unroll
                for (int j = 0; j < 8; ++j)
                    acc[i][j] = fmaf(a[i], b[j], acc[i][j]);
        }
        __syncthreads();
    }

#pragma unroll
    for (int i = 0; i < 8; ++i) {
        const int row = m0 + mf + (i & 3) + (i >> 2) * 64;
        const float4 v0 = make_float4(acc[i][0], acc[i][1], acc[i][2], acc[i][3]);
        const float4 v1 = make_float4(acc[i][4], acc[i][5], acc[i][6], acc[i][7]);
        *(float4*)(z + (size_t)row * HIDDEN + n0 + nf)      = v0;
        *(float4*)(z + (size_t)row * HIDDEN + n0 + nf + 64) = v1;
    }
}

__global__ __launch_bounds__(256, 2)
void topk_decode_fb(float* __restrict__ z,
                    const float* __restrict__ dA, const float* __restrict__ dB,
                    const float* __restrict__ po0, const float* __restrict__ po1,
                    float* __restrict__ rec0, float* __restrict__ rec1)
{
    __shared__ float    rowv[HIDDEN];
    __shared__ unsigned hist[4][257];
    __shared__ unsigned scanbuf[256];
    __shared__ float    selv[TOPK];
    __shared__ int      seli[TOPK];
    __shared__ unsigned sh_byte, sh_gt;

    const int tid = threadIdx.x;
    const size_t rowid = blockIdx.x;
    float* __restrict__ zrow = z + rowid * HIDDEN;

#pragma unroll
    for (int s = 0; s < 8; ++s) {
        const int i4 = s * 256 + tid;
        *(float4*)&rowv[i4 * 4] = *(const float4*)&zrow[i4 * 4];
    }
    __syncthreads();

    unsigned prefix = 0, prefmask = 0, need = TOPK;
#pragma unroll
    for (int p = 3; p >= 0; --p) {
        for (int i = tid; i < 4 * 257; i += 256) (&hist[0][0])[i] = 0;
        __syncthreads();
        const int sh = p * 8;
        for (int s = 0; s < 32; ++s) {
            const int i = s * 256 + tid;
            const unsigned k = fkey(rowv[i]);
            if ((k & prefmask) == prefix)
                atomicAdd(&hist[tid & 3][(k >> sh) & 255], 1);
        }
        __syncthreads();
        const unsigned tot = hist[0][tid] + hist[1][tid] + hist[2][tid] + hist[3][tid];
        hist[0][tid] = tot;
        __syncthreads();
        if (tid == 0) {
            unsigned cum = 0;
            int b = 255;
            for (;; --b) {
                const unsigned c = hist[0][b];
                if (cum + c >= need || b == 0) { sh_byte = (unsigned)b; sh_gt = cum; break; }
                cum += c;
            }
        }
        __syncthreads();
        prefix  |= sh_byte << sh;
        prefmask |= 0xFFu << sh;
        need -= sh_gt;
        __syncthreads();
    }
    const unsigned cut = prefix;
    const unsigned needEq = need;

    unsigned gtmask = 0, eqmask = 0;
#pragma unroll
    for (int j = 0; j < 32; ++j) {
        const int jr = (j + tid) & 31;
        const int i = tid * 32 + jr;
        const unsigned k = fkey(rowv[i]);
        if (k > cut)       gtmask |= 1u << jr;
        else if (k == cut) eqmask |= 1u << jr;
    }

    scanbuf[tid] = __popc(eqmask);
    __syncthreads();
    for (int off = 1; off < 256; off <<= 1) {
        const unsigned v = scanbuf[tid];
        const unsigned add = (tid >= off) ? scanbuf[tid - off] : 0u;
        __syncthreads();
        scanbuf[tid] = v + add;
        __syncthreads();
    }
    const unsigned eqexc = scanbuf[tid] - __popc(eqmask);
    __syncthreads();

    unsigned selmask = gtmask;
    {
        unsigned m = eqmask, r = eqexc;
        while (m) {
            const int j = __ffs(m) - 1;
            if (r < needEq) selmask |= 1u << j;
            ++r;
            m &= m - 1;
        }
    }

    scanbuf[tid] = __popc(selmask);
    __syncthreads();
    for (int off = 1; off < 256; off <<= 1) {
        const unsigned v = scanbuf[tid];
        const unsigned add = (tid >= off) ? scanbuf[tid - off] : 0u;
        __syncthreads();
        scanbuf[tid] = v + add;
        __syncthreads();
    }
    const unsigned selexc = scanbuf[tid] - __popc(selmask);

#pragma unroll
    for (int j = 0; j < 32; ++j) {
        const int jr = (j + tid) & 31;
        const int i = tid * 32 + jr;
        if ((selmask >> jr) & 1u) {
            const int slot = (int)(selexc + __popc(selmask & ((1u << jr) - 1u)));
            selv[slot] = rowv[i];
            seli[slot] = i;
        } else {
            rowv[i] = 0.0f;
        }
    }
    __syncthreads();

#pragma unroll
    for (int s = 0; s < 8; ++s) {
        const int i4 = s * 256 + tid;
        *(float4*)&zrow[i4 * 4] = *(float4*)&rowv[i4 * 4];
    }

    for (int d = tid; d < DIM0; d += 256) {
        float a = po0[d];
#pragma unroll
        for (int j = 0; j < TOPK; ++j)
            a = fmaf(selv[j], dA[(size_t)d * HIDDEN + seli[j]], a);
        rec0[rowid * DIM0 + d] = a;
    }
    for (int d = tid; d < DIM1; d += 256) {
        float a = po1[d];
#pragma unroll
        for (int j = 0; j < TOPK; ++j)
            a = fmaf(selv[j], dB[(size_t)d * HIDDEN + seli[j]], a);
        rec1[rowid * DIM1 + d] = a;
    }
}

// ===========================================================================
extern "C" void kernel_launch(void* const* d_in, const int* in_sizes, int n_in,
                              void* d_out, int out_size, void* d_ws, size_t ws_size,
                              hipStream_t stream)
{
    const float* x0  = (const float*)d_in[0];
    const float* x1  = (const float*)d_in[1];
    const float* pb0 = (const float*)d_in[2];
    const float* pb1 = (const float*)d_in[3];
    const float* ew0 = (const float*)d_in[4];
    const float* ew1 = (const float*)d_in[5];
    const float* dw0 = (const float*)d_in[6];
    const float* dw1 = (const float*)d_in[7];
    const float* po0 = (const float*)d_in[8];
    const float* po1 = (const float*)d_in[9];
    const int*  srcp = (const int*)d_in[10];

    float* z    = (float*)d_out;
    float* rec0 = z + (size_t)BATCH * HIDDEN;
    float* rec1 = rec0 + (size_t)BATCH * DIM0;

    // ws layout (bf16): xb[B][768] | wb[H][768] | dTb0[H][512] | dTb1[H][768]
    unsigned short* xb   = (unsigned short*)d_ws;
    unsigned short* wb   = xb   + (size_t)BATCH * DIM1;
    unsigned short* dTb0 = wb   + (size_t)HIDDEN * DIM1;
    unsigned short* dTb1 = dTb0 + (size_t)HIDDEN * DIM0;
    const size_t need = ((size_t)BATCH * DIM1 + (size_t)HIDDEN * DIM1 +
                         (size_t)HIDDEN * DIM0 + (size_t)HIDDEN * DIM1) * sizeof(unsigned short);

    if (ws_size >= need) {
        convert_xw<<<4096, 256, 0, stream>>>(x0, x1, pb0, pb1, ew0, ew1, srcp, xb, wb);
        dim3 tb(32, 8);
        transpose_dec_bf16<<<dim3(HIDDEN / 32, DIM0 / 32), tb, 0, stream>>>(dw0, dTb0, DIM0);
        transpose_dec_bf16<<<dim3(HIDDEN / 32, DIM1 / 32), tb, 0, stream>>>(dw1, dTb1, DIM1);
        gemm_bf16<<<(BATCH / 128) * (HIDDEN / 128), 256, 0, stream>>>(xb, wb, srcp, z);
        topk_rescore_decode<<<BATCH, 256, 0, stream>>>(
            z, x0, x1, pb0, pb1, ew0, ew1, dTb0, dTb1, po0, po1, rec0, rec1, srcp);
    } else {
        encode_gemm<<<dim3(HIDDEN / 128, BATCH / 128), 256, 0, stream>>>(
            x0, x1, pb0, pb1, ew0, ew1, srcp, z);
        topk_decode_fb<<<BATCH, 256, 0, stream>>>(z, dw0, dw1, po0, po1, rec0, rec1);
    }
}

// Round 3
// 750.798 us; speedup vs baseline: 3.3267x; 1.1814x over previous
//
#include <hip/hip_runtime.h>

// UniversalSAE: z = TopK32((x - pre_bias) @ enc_w.T), rec_i = z @ dec_w_i.T + post_bias_i
// R3: bf16 MFMA screening GEMM (stores bf16 scores in-place in z rows) +
// u16-bisect screening + 8-lane-group coalesced exact fp32 rescore +
// bf16 transposed decode. Fallback = round-1 known-pass fp32 path.

#define BATCH  16384
#define HIDDEN 8192
#define DIM0   512
#define DIM1   768
#define TOPK   32
#define CAND_MAX 256
#define WIN_LO 40
#define WIN_HI 96

typedef __attribute__((ext_vector_type(8))) short bf16x8;
typedef __attribute__((ext_vector_type(8))) unsigned short u16x8;
typedef __attribute__((ext_vector_type(4))) float f32x4;

__device__ __forceinline__ unsigned fkey(float f) {
    unsigned u = __float_as_uint(f);
    return (u & 0x80000000u) ? ~u : (u | 0x80000000u);
}
__device__ __forceinline__ unsigned fkey16(unsigned short h) {
    return (h & 0x8000u) ? (unsigned)((~h) & 0xFFFFu) : (unsigned)(h | 0x8000u);
}
__device__ __forceinline__ unsigned short f2b(float f) {  // fp32 -> bf16 RNE
    unsigned u = __float_as_uint(f);
    unsigned r = (u + 0x7FFFu + ((u >> 16) & 1u)) >> 16;
    return (unsigned short)r;
}
__device__ __forceinline__ float b2f(unsigned short h) {
    return __uint_as_float(((unsigned)h) << 16);
}
__device__ __forceinline__ void load_lds16(const void* g, void* l) {
    __builtin_amdgcn_global_load_lds((const __attribute__((address_space(1))) void*)g,
                                     (__attribute__((address_space(3))) void*)l, 16, 0, 0);
}

// ===========================================================================
// NEW PATH
// ===========================================================================

__global__ void convert_xw(const float* __restrict__ x0, const float* __restrict__ x1,
                           const float* __restrict__ pb0, const float* __restrict__ pb1,
                           const float* __restrict__ w0, const float* __restrict__ w1,
                           const int* __restrict__ srcp,
                           unsigned short* __restrict__ xb, unsigned short* __restrict__ wb)
{
    const int src = *srcp;
    const float* __restrict__ x  = src ? x1  : x0;
    const float* __restrict__ pb = src ? pb1 : pb0;
    const float* __restrict__ w  = src ? w1  : w0;
    const int D = src ? DIM1 : DIM0;
    const int nx4 = BATCH * D / 4;
    const int nw4 = HIDDEN * D / 4;
    for (int i = blockIdx.x * blockDim.x + threadIdx.x; i < nx4 + nw4;
         i += gridDim.x * blockDim.x) {
        if (i < nx4) {
            float4 v = ((const float4*)x)[i];
            const int k = (i * 4) % D;
            v.x -= pb[k]; v.y -= pb[k + 1]; v.z -= pb[k + 2]; v.w -= pb[k + 3];
            ushort4 o; o.x = f2b(v.x); o.y = f2b(v.y); o.z = f2b(v.z); o.w = f2b(v.w);
            ((ushort4*)xb)[i] = o;
        } else {
            const float4 v = ((const float4*)w)[i - nx4];
            ushort4 o; o.x = f2b(v.x); o.y = f2b(v.y); o.z = f2b(v.z); o.w = f2b(v.w);
            ((ushort4*)wb)[i - nx4] = o;
        }
    }
}

__global__ void transpose_dec_bf16(const float* __restrict__ dec,
                                   unsigned short* __restrict__ decT, int DD)
{
    __shared__ float t[32][33];
    const int hb = blockIdx.x * 32, db = blockIdx.y * 32;
    const int lx = threadIdx.x, ly = threadIdx.y;
#pragma unroll
    for (int s = 0; s < 32; s += 8)
        t[ly + s][lx] = dec[(size_t)(db + ly + s) * HIDDEN + hb + lx];
    __syncthreads();
#pragma unroll
    for (int s = 0; s < 32; s += 8)
        decT[(size_t)(hb + ly + s) * DD + db + lx] = f2b(t[lx][ly + s]);
}

// ---- bf16 MFMA GEMM; stores bf16 approx scores into the FIRST 16KB of each
//      fp32 z row (block-private region -> no cross-block aliasing) ----
__global__ __launch_bounds__(256, 2)
void gemm_bf16(const unsigned short* __restrict__ xb, const unsigned short* __restrict__ wb,
               const int* __restrict__ srcp, float* __restrict__ z)
{
    const int D = (*srcp == 0) ? DIM0 : DIM1;

    __shared__ unsigned short As[128 * 64];
    __shared__ unsigned short Bs[128 * 64];

    const int nwg = gridDim.x;
    int id = blockIdx.x;
    id = (id & 7) * (nwg >> 3) + (id >> 3);      // XCD swizzle (nwg % 8 == 0)
    const int bx = id & 63;
    const int by = id >> 6;
    const int m0 = by * 128, n0 = bx * 128;

    const int tid  = threadIdx.x;
    const int lane = tid & 63;
    const int wid  = tid >> 6;
    const int wr   = wid >> 1;
    const int wc   = wid & 1;
    const int l15  = lane & 15;
    const int g    = lane >> 4;

    f32x4 acc[4][4];
#pragma unroll
    for (int i = 0; i < 4; ++i)
#pragma unroll
        for (int j = 0; j < 4; ++j) acc[i][j] = (f32x4){0.f, 0.f, 0.f, 0.f};

    for (int k0 = 0; k0 < D; k0 += 64) {
#pragma unroll
        for (int q = 0; q < 4; ++q) {
            const int c   = wid * 256 + q * 64 + lane;
            const int row = c >> 3, jb = c & 7;
            const int j   = jb ^ (row & 7);      // pre-swizzled source (rule #21)
            load_lds16(xb + (size_t)(m0 + row) * D + k0 + j * 8,
                       As + (size_t)(wid * 256 + q * 64) * 8);
            load_lds16(wb + (size_t)(n0 + row) * D + k0 + j * 8,
                       Bs + (size_t)(wid * 256 + q * 64) * 8);
        }
        __syncthreads();

#pragma unroll
        for (int kk = 0; kk < 2; ++kk) {
            bf16x8 a[4], b[4];
#pragma unroll
            for (int f = 0; f < 4; ++f) {
                const int rA = wr * 64 + f * 16 + l15;
                const int sA = ((kk * 4 + g) ^ (rA & 7)) * 16;
                a[f] = *(const bf16x8*)((const char*)As + rA * 128 + sA);
                const int rB = wc * 64 + f * 16 + l15;
                const int sB = ((kk * 4 + g) ^ (rB & 7)) * 16;
                b[f] = *(const bf16x8*)((const char*)Bs + rB * 128 + sB);
            }
#pragma unroll
            for (int fi = 0; fi < 4; ++fi)
#pragma unroll
                for (int fj = 0; fj < 4; ++fj)
                    acc[fi][fj] = __builtin_amdgcn_mfma_f32_16x16x32_bf16(
                        a[fi], b[fj], acc[fi][fj], 0, 0, 0);
        }
        __syncthreads();
    }

    // epilogue: bf16 scores at byte offset row*(HIDDEN*4), col*2
#pragma unroll
    for (int fi = 0; fi < 4; ++fi) {
        const int row = m0 + wr * 64 + fi * 16 + g * 4;
#pragma unroll
        for (int fj = 0; fj < 4; ++fj) {
            const int col = n0 + wc * 64 + fj * 16 + l15;
#pragma unroll
            for (int r = 0; r < 4; ++r) {
                unsigned short* zs =
                    (unsigned short*)((char*)z + (size_t)(row + r) * (HIDDEN * 4));
                zs[col] = f2b(acc[fi][fj][r]);
            }
        }
    }
}

// ---- per-row: u16 bisect -> candidates -> group-coalesced exact fp32 rescore
//      -> exact top-32 -> sparse z + decode ----
__global__ __launch_bounds__(256)
void topk_rescore_decode(float* __restrict__ z,
                         const float* __restrict__ x0, const float* __restrict__ x1,
                         const float* __restrict__ pb0, const float* __restrict__ pb1,
                         const float* __restrict__ ew0, const float* __restrict__ ew1,
                         const unsigned short* __restrict__ dTb0,
                         const unsigned short* __restrict__ dTb1,
                         const float* __restrict__ po0, const float* __restrict__ po1,
                         float* __restrict__ rec0, float* __restrict__ rec1,
                         const int* __restrict__ srcp)
{
    const int src = *srcp;
    const float* __restrict__ xsrc = src ? x1 : x0;
    const float* __restrict__ pb   = src ? pb1 : pb0;
    const float* __restrict__ ew   = src ? ew1 : ew0;
    const int D = src ? DIM1 : DIM0;

    __shared__ float         xs[DIM1];
    __shared__ int           cidx[CAND_MAX];
    __shared__ float         cval[CAND_MAX];
    __shared__ unsigned char cflag[CAND_MAX];
    __shared__ int           counts[4];
    __shared__ int           s_cnt;
    __shared__ float         selv[TOPK];
    __shared__ int           seli[TOPK];

    const int tid = threadIdx.x;
    const size_t row = blockIdx.x;
    float* __restrict__ zrow = z + row * HIDDEN;
    const unsigned short* __restrict__ zsrow =
        (const unsigned short*)((const char*)z + row * (HIDDEN * 4));

    // 32 bf16 keys per thread (16B coalesced reads)
    unsigned key[32];
#pragma unroll
    for (int s = 0; s < 4; ++s) {
        const u16x8 v = *(const u16x8*)(zsrow + (size_t)(s * 256 + tid) * 8);
#pragma unroll
        for (int j = 0; j < 8; ++j) key[s * 8 + j] = fkey16(v[j]);
    }

    // stage exact (x - pb) row
    for (int d = tid; d < D; d += 256) xs[d] = xsrc[row * D + d] - pb[d];
    if (tid == 0) s_cnt = 0;
    __syncthreads();

    // bisect u16 key space: count(key > kappa) in [WIN_LO, WIN_HI]
    unsigned lo = 0u, hi = 65535u, kappa = 0u;
    int found = 0;
    for (int it = 0; it < 18; ++it) {
        const unsigned mid = (lo + hi) >> 1;
        int c = 0;
#pragma unroll
        for (int j = 0; j < 32; ++j) c += (key[j] > mid) ? 1 : 0;
#pragma unroll
        for (int off = 32; off; off >>= 1) c += __shfl_xor(c, off);
        if ((tid & 63) == 0) counts[tid >> 6] = c;
        __syncthreads();
        const int tot = counts[0] + counts[1] + counts[2] + counts[3];
        __syncthreads();
        if (tot >= WIN_LO && tot <= WIN_HI) { kappa = mid; found = 1; break; }
        if (tot > WIN_HI) lo = mid; else hi = mid;
        if (hi - lo <= 1u) break;
    }
    if (!found) kappa = lo;   // count(lo) > WIN_HI; CAND_MAX=256 absorbs ties

    // collect candidate indices
#pragma unroll
    for (int j = 0; j < 32; ++j) {
        if (key[j] > kappa) {
            const int slot = atomicAdd(&s_cnt, 1);
            if (slot < CAND_MAX)
                cidx[slot] = ((j >> 3) * 256 + tid) * 8 + (j & 7);
        }
    }
    __syncthreads();
    const int C = min(s_cnt, CAND_MAX);

    // exact fp32 rescore: 8-lane groups, 128B-coalesced row streaming,
    // 4-wide accumulators + shfl tree (error ~1e-5 << selection gap ~3.6e-3)
    {
        const int grp = tid >> 3, j8 = tid & 7;
        for (int c = grp; c < C; c += 32) {
            const float* __restrict__ wrow = ew + (size_t)cidx[c] * D;
            float4 a4 = make_float4(0.f, 0.f, 0.f, 0.f);
            for (int s = 0; s < D; s += 32) {
                const float4 w4 = *(const float4*)&wrow[s + j8 * 4];
                const float4 x4 = *(const float4*)&xs[s + j8 * 4];
                a4.x = fmaf(x4.x, w4.x, a4.x);
                a4.y = fmaf(x4.y, w4.y, a4.y);
                a4.z = fmaf(x4.z, w4.z, a4.z);
                a4.w = fmaf(x4.w, w4.w, a4.w);
            }
            float a = (a4.x + a4.y) + (a4.z + a4.w);
            a += __shfl_xor(a, 1);
            a += __shfl_xor(a, 2);
            a += __shfl_xor(a, 4);
            if (j8 == 0) cval[c] = a;
        }
    }
    __syncthreads();

    // exact top-32 among C candidates (val desc, idx asc)
    if (tid < C) {
        const float v = cval[tid];
        const int  ix = cidx[tid];
        int rank = 0;
        for (int j = 0; j < C; ++j) {
            const float vj = cval[j];
            rank += (vj > v || (vj == v && cidx[j] < ix)) ? 1 : 0;
        }
        cflag[tid] = (rank < TOPK) ? 1 : 0;
    }
    __syncthreads();
    if (tid < C && cflag[tid]) {
        const int ix = cidx[tid];
        int sr = 0;
        for (int j = 0; j < C; ++j) sr += (cflag[j] && cidx[j] < ix) ? 1 : 0;
        selv[sr] = cval[tid];
        seli[sr] = ix;
    }
    __syncthreads();

    // zero-fill z row (keys already in registers), then scatter 32 exact values
    const float4 z4 = make_float4(0.f, 0.f, 0.f, 0.f);
#pragma unroll
    for (int s = 0; s < 8; ++s)
        *(float4*)&zrow[(size_t)(s * 256 + tid) * 4] = z4;
    __syncthreads();
    if (tid < TOPK) zrow[seli[tid]] = selv[tid];

    // sparse decode (ascending index order)
    for (int d = tid; d < DIM0; d += 256) {
        float a = po0[d];
#pragma unroll
        for (int j = 0; j < TOPK; ++j)
            a = fmaf(selv[j], b2f(dTb0[(size_t)seli[j] * DIM0 + d]), a);
        rec0[row * DIM0 + d] = a;
    }
    for (int d = tid; d < DIM1; d += 256) {
        float a = po1[d];
#pragma unroll
        for (int j = 0; j < TOPK; ++j)
            a = fmaf(selv[j], b2f(dTb1[(size_t)seli[j] * DIM1 + d]), a);
        rec1[row * DIM1 + d] = a;
    }
}

// ===========================================================================
// FALLBACK PATH (round-1, known-pass) — used only if ws is too small
// ===========================================================================

__global__ __launch_bounds__(256, 2)
void encode_gemm(const float* __restrict__ x0, const float* __restrict__ x1,
                 const float* __restrict__ pb0, const float* __restrict__ pb1,
                 const float* __restrict__ w0, const float* __restrict__ w1,
                 const int* __restrict__ srcp, float* __restrict__ z)
{
    const int src = *srcp;
    const float* __restrict__ x  = (src == 0) ? x0 : x1;
    const float* __restrict__ pb = (src == 0) ? pb0 : pb1;
    const float* __restrict__ w  = (src == 0) ? w0 : w1;
    const int D = (src == 0) ? DIM0 : DIM1;

    __shared__ float As[16][132];
    __shared__ float Bs[16][132];

    const int tid = threadIdx.x;
    const int m0 = blockIdx.y * 128;
    const int n0 = blockIdx.x * 128;

    const int cA0 = tid,          cA1 = tid + 256;
    const int r0  = cA0 >> 2,     kq0 = (cA0 & 3) * 4;
    const int r1  = cA1 >> 2,     kq1 = (cA1 & 3) * 4;

    const int mf = (tid & 15) * 4;
    const int nf = (tid >> 4) * 4;

    float acc[8][8];
#pragma unroll
    for (int i = 0; i < 8; ++i)
#pragma unroll
        for (int j = 0; j < 8; ++j) acc[i][j] = 0.0f;

    for (int k0 = 0; k0 < D; k0 += 16) {
        const float4 av0 = *(const float4*)(x + (size_t)(m0 + r0) * D + k0 + kq0);
        const float4 av1 = *(const float4*)(x + (size_t)(m0 + r1) * D + k0 + kq1);
        const float4 pv0 = *(const float4*)(pb + k0 + kq0);
        const float4 pv1 = *(const float4*)(pb + k0 + kq1);
        const float4 bv0 = *(const float4*)(w + (size_t)(n0 + r0) * D + k0 + kq0);
        const float4 bv1 = *(const float4*)(w + (size_t)(n0 + r1) * D + k0 + kq1);
        As[kq0 + 0][r0] = av0.x - pv0.x;
        As[kq0 + 1][r0] = av0.y - pv0.y;
        As[kq0 + 2][r0] = av0.z - pv0.z;
        As[kq0 + 3][r0] = av0.w - pv0.w;
        As[kq1 + 0][r1] = av1.x - pv1.x;
        As[kq1 + 1][r1] = av1.y - pv1.y;
        As[kq1 + 2][r1] = av1.z - pv1.z;
        As[kq1 + 3][r1] = av1.w - pv1.w;
        Bs[kq0 + 0][r0] = bv0.x;
        Bs[kq0 + 1][r0] = bv0.y;
        Bs[kq0 + 2][r0] = bv0.z;
        Bs[kq0 + 3][r0] = bv0.w;
        Bs[kq1 + 0][r1] = bv1.x;
        Bs[kq1 + 1][r1] = bv1.y;
        Bs[kq1 + 2][r1] = bv1.z;
        Bs[kq1 + 3][r1] = bv1.w;
        __syncthreads();
#pragma unroll
        for (int kk = 0; kk < 16; ++kk) {
            const float4 A0 = *(const float4*)&As[kk][mf];
            const float4 A1 = *(const float4*)&As[kk][mf + 64];
            const float4 B0 = *(const float4*)&Bs[kk][nf];
            const float4 B1 = *(const float4*)&Bs[kk][nf + 64];
            const float a[8] = {A0.x, A0.y, A0.z, A0.w, A1.x, A1.y, A1.z, A1.w};
            const float b[8] = {B0.x, B0.y, B0.z, B0.w, B1.x, B1.y, B1.z, B1.w};
#pragma unroll
            for (int i = 0; i < 8; ++i)
#pragma unroll
                for (int j = 0; j < 8; ++j)
                    acc[i][j] = fmaf(a[i], b[j], acc[i][j]);
        }
        __syncthreads();
    }

#pragma unroll
    for (int i = 0; i < 8; ++i) {
        const int row = m0 + mf + (i & 3) + (i >> 2) * 64;
        const float4 v0 = make_float4(acc[i][0], acc[i][1], acc[i][2], acc[i][3]);
        const float4 v1 = make_float4(acc[i][4], acc[i][5], acc[i][6], acc[i][7]);
        *(float4*)(z + (size_t)row * HIDDEN + n0 + nf)      = v0;
        *(float4*)(z + (size_t)row * HIDDEN + n0 + nf + 64) = v1;
    }
}

__global__ __launch_bounds__(256, 2)
void topk_decode_fb(float* __restrict__ z,
                    const float* __restrict__ dA, const float* __restrict__ dB,
                    const float* __restrict__ po0, const float* __restrict__ po1,
                    float* __restrict__ rec0, float* __restrict__ rec1)
{
    __shared__ float    rowv[HIDDEN];
    __shared__ unsigned hist[4][257];
    __shared__ unsigned scanbuf[256];
    __shared__ float    selv[TOPK];
    __shared__ int      seli[TOPK];
    __shared__ unsigned sh_byte, sh_gt;

    const int tid = threadIdx.x;
    const size_t rowid = blockIdx.x;
    float* __restrict__ zrow = z + rowid * HIDDEN;

#pragma unroll
    for (int s = 0; s < 8; ++s) {
        const int i4 = s * 256 + tid;
        *(float4*)&rowv[i4 * 4] = *(const float4*)&zrow[i4 * 4];
    }
    __syncthreads();

    unsigned prefix = 0, prefmask = 0, need = TOPK;
#pragma unroll
    for (int p = 3; p >= 0; --p) {
        for (int i = tid; i < 4 * 257; i += 256) (&hist[0][0])[i] = 0;
        __syncthreads();
        const int sh = p * 8;
        for (int s = 0; s < 32; ++s) {
            const int i = s * 256 + tid;
            const unsigned k = fkey(rowv[i]);
            if ((k & prefmask) == prefix)
                atomicAdd(&hist[tid & 3][(k >> sh) & 255], 1);
        }
        __syncthreads();
        const unsigned tot = hist[0][tid] + hist[1][tid] + hist[2][tid] + hist[3][tid];
        hist[0][tid] = tot;
        __syncthreads();
        if (tid == 0) {
            unsigned cum = 0;
            int b = 255;
            for (;; --b) {
                const unsigned c = hist[0][b];
                if (cum + c >= need || b == 0) { sh_byte = (unsigned)b; sh_gt = cum; break; }
                cum += c;
            }
        }
        __syncthreads();
        prefix  |= sh_byte << sh;
        prefmask |= 0xFFu << sh;
        need -= sh_gt;
        __syncthreads();
    }
    const unsigned cut = prefix;
    const unsigned needEq = need;

    unsigned gtmask = 0, eqmask = 0;
#pragma unroll
    for (int j = 0; j < 32; ++j) {
        const int jr = (j + tid) & 31;
        const int i = tid * 32 + jr;
        const unsigned k = fkey(rowv[i]);
        if (k > cut)       gtmask |= 1u << jr;
        else if (k == cut) eqmask |= 1u << jr;
    }

    scanbuf[tid] = __popc(eqmask);
    __syncthreads();
    for (int off = 1; off < 256; off <<= 1) {
        const unsigned v = scanbuf[tid];
        const unsigned add = (tid >= off) ? scanbuf[tid - off] : 0u;
        __syncthreads();
        scanbuf[tid] = v + add;
        __syncthreads();
    }
    const unsigned eqexc = scanbuf[tid] - __popc(eqmask);
    __syncthreads();

    unsigned selmask = gtmask;
    {
        unsigned m = eqmask, r = eqexc;
        while (m) {
            const int j = __ffs(m) - 1;
            if (r < needEq) selmask |= 1u << j;
            ++r;
            m &= m - 1;
        }
    }

    scanbuf[tid] = __popc(selmask);
    __syncthreads();
    for (int off = 1; off < 256; off <<= 1) {
        const unsigned v = scanbuf[tid];
        const unsigned add = (tid >= off) ? scanbuf[tid - off] : 0u;
        __syncthreads();
        scanbuf[tid] = v + add;
        __syncthreads();
    }
    const unsigned selexc = scanbuf[tid] - __popc(selmask);

#pragma unroll
    for (int j = 0; j < 32; ++j) {
        const int jr = (j + tid) & 31;
        const int i = tid * 32 + jr;
        if ((selmask >> jr) & 1u) {
            const int slot = (int)(selexc + __popc(selmask & ((1u << jr) - 1u)));
            selv[slot] = rowv[i];
            seli[slot] = i;
        } else {
            rowv[i] = 0.0f;
        }
    }
    __syncthreads();

#pragma unroll
    for (int s = 0; s < 8; ++s) {
        const int i4 = s * 256 + tid;
        *(float4*)&zrow[i4 * 4] = *(float4*)&rowv[i4 * 4];
    }

    for (int d = tid; d < DIM0; d += 256) {
        float a = po0[d];
#pragma unroll
        for (int j = 0; j < TOPK; ++j)
            a = fmaf(selv[j], dA[(size_t)d * HIDDEN + seli[j]], a);
        rec0[rowid * DIM0 + d] = a;
    }
    for (int d = tid; d < DIM1; d += 256) {
        float a = po1[d];
#pragma unroll
        for (int j = 0; j < TOPK; ++j)
            a = fmaf(selv[j], dB[(size_t)d * HIDDEN + seli[j]], a);
        rec1[rowid * DIM1 + d] = a;
    }
}

// ===========================================================================
extern "C" void kernel_launch(void* const* d_in, const int* in_sizes, int n_in,
                              void* d_out, int out_size, void* d_ws, size_t ws_size,
                              hipStream_t stream)
{
    const float* x0  = (const float*)d_in[0];
    const float* x1  = (const float*)d_in[1];
    const float* pb0 = (const float*)d_in[2];
    const float* pb1 = (const float*)d_in[3];
    const float* ew0 = (const float*)d_in[4];
    const float* ew1 = (const float*)d_in[5];
    const float* dw0 = (const float*)d_in[6];
    const float* dw1 = (const float*)d_in[7];
    const float* po0 = (const float*)d_in[8];
    const float* po1 = (const float*)d_in[9];
    const int*  srcp = (const int*)d_in[10];

    float* z    = (float*)d_out;
    float* rec0 = z + (size_t)BATCH * HIDDEN;
    float* rec1 = rec0 + (size_t)BATCH * DIM0;

    // ws layout (bf16): xb[B][768] | wb[H][768] | dTb0[H][512] | dTb1[H][768]
    unsigned short* xb   = (unsigned short*)d_ws;
    unsigned short* wb   = xb   + (size_t)BATCH * DIM1;
    unsigned short* dTb0 = wb   + (size_t)HIDDEN * DIM1;
    unsigned short* dTb1 = dTb0 + (size_t)HIDDEN * DIM0;
    const size_t need = ((size_t)BATCH * DIM1 + (size_t)HIDDEN * DIM1 +
                         (size_t)HIDDEN * DIM0 + (size_t)HIDDEN * DIM1) * sizeof(unsigned short);

    if (ws_size >= need) {
        convert_xw<<<4096, 256, 0, stream>>>(x0, x1, pb0, pb1, ew0, ew1, srcp, xb, wb);
        dim3 tb(32, 8);
        transpose_dec_bf16<<<dim3(HIDDEN / 32, DIM0 / 32), tb, 0, stream>>>(dw0, dTb0, DIM0);
        transpose_dec_bf16<<<dim3(HIDDEN / 32, DIM1 / 32), tb, 0, stream>>>(dw1, dTb1, DIM1);
        gemm_bf16<<<(BATCH / 128) * (HIDDEN / 128), 256, 0, stream>>>(xb, wb, srcp, z);
        topk_rescore_decode<<<BATCH, 256, 0, stream>>>(
            z, x0, x1, pb0, pb1, ew0, ew1, dTb0, dTb1, po0, po1, rec0, rec1, srcp);
    } else {
        encode_gemm<<<dim3(HIDDEN / 128, BATCH / 128), 256, 0, stream>>>(
            x0, x1, pb0, pb1, ew0, ew1, srcp, z);
        topk_decode_fb<<<BATCH, 256, 0, stream>>>(z, dw0, dw1, po0, po1, rec0, rec1);
    }
}